// Round 9
// baseline (337.378 us; speedup 1.0000x reference)
//
#include <hip/hip_runtime.h>
#include <hip/hip_bf16.h>
#include <math.h>

// Problem constants
#define BB   32
#define HN   12
#define N1   256
#define N2   320
#define SS   256
#define BH   (BB*HN)                 // 384
#define ROWS (BH*N1)                 // 98304 rows per tensor
#define R4   (N2/4)                  // 80 float4 per row
#define N4PT ((size_t)ROWS*R4)       // float4 per tensor = 7,864,320

// Persistent grid: 512 blocks x 256 threads, 2 blocks/CU guaranteed resident
// (launch_bounds(256,2): any VGPR<=256 + 6.2KB LDS fits 2 blocks on every CU).
#define GRID      512
#define NWAVES    (GRID*4)               // 2048
#define ROWS_TOTAL (2*ROWS)              // 196608
#define RPW       (ROWS_TOTAL/NWAVES)    // 96 rows per wave
#define C_HALF    (GRID/2)               // 256 blocks per tensor in phase C
#define C_F4_BLK  ((unsigned)(N4PT/C_HALF))   // 30720 f4 per block
#define C_ITERS   ((int)(C_F4_BLK/256))       // 120 per thread

typedef float v4f __attribute__((ext_vector_type(4)));

// Grid-wide barrier: arrive (device-scope RMW) + spin on agent-scope atomic
// load with s_sleep backoff. Counter is single-use per call (zeroed by
// hipMemsetAsync in kernel_launch). __threadfence() on the writer side
// flushes the XCD L2 (wbl2); on the reader side it invalidates (inv), so
// cross-XCD data written before the barrier is visible after it.
__device__ __forceinline__ void grid_barrier(unsigned* bar)
{
    __syncthreads();                       // all block stores issued+vmcnt'd
    if (threadIdx.x == 0) {
        __threadfence();                   // release: flush L2 to coherence pt
        atomicAdd(bar, 1u);
        while (__hip_atomic_load(bar, __ATOMIC_ACQUIRE,
                                 __HIP_MEMORY_SCOPE_AGENT) < (unsigned)GRID)
            __builtin_amdgcn_s_sleep(16);
        __threadfence();                   // acquire: invalidate stale lines
    }
    __syncthreads();
}

__global__ __launch_bounds__(256, 2) void k_all(
    const float* __restrict__ rgb, const float* __restrict__ tir,
    const int*   __restrict__ gidx,
    const float* __restrict__ ln_g, const float* __restrict__ ln_b,
    const float* __restrict__ W1,  const float* __restrict__ b1,
    const float* __restrict__ W2,  const float* __restrict__ b2,
    unsigned* __restrict__ bar0, unsigned* __restrict__ bar1,
    float* __restrict__ mxr,   float* __restrict__ mxt,
    float* __restrict__ growR, float* __restrict__ growT,
    v4f* __restrict__ outTir,  v4f* __restrict__ outRgb)
{
    __shared__ float v[2 * SS];
    __shared__ float hs[SS];
    __shared__ float gs[2 * SS];
    __shared__ int   sidx_s[SS];
    __shared__ float red[8];

    const int t    = (int)threadIdx.x;
    const int blk  = (int)blockIdx.x;
    const int w    = t >> 6;
    const int lane = t & 63;

    // ---- Phase A: rowmax; 96 contiguous rows per wave, 8-row load batches --
    {
        const int gw    = blk * 4 + w;           // 0..2047
        const int isTir = gw >= (NWAVES / 2);    // waves [1024,2048) -> tir
        const float* src = isTir ? tir : rgb;
        float*       dst = isTir ? mxt : mxr;
        const int r0 = (isTir ? gw - NWAVES / 2 : gw) * RPW;

        for (int rr = 0; rr < RPW; rr += 8) {
            v4f a[8], b8[8];
#pragma unroll
            for (int q = 0; q < 8; ++q) {
                const v4f* p = (const v4f*)(src + (size_t)(r0 + rr + q) * N2);
                a[q]  = p[lane];
                // tail f4s [64,80): lane-duplicated (no effect on max; dup
                // addresses coalesce to the same cache lines)
                b8[q] = p[64 + (lane & 15)];
            }
#pragma unroll
            for (int q = 0; q < 8; ++q) {
                float m = fmaxf(fmaxf(fmaxf(a[q].x, a[q].y), fmaxf(a[q].z, a[q].w)),
                                fmaxf(fmaxf(b8[q].x, b8[q].y), fmaxf(b8[q].z, b8[q].w)));
#pragma unroll
                for (int off = 32; off; off >>= 1) m = fmaxf(m, __shfl_xor(m, off));
                if (lane == 0) dst[r0 + rr + q] = m;
            }
        }
    }
    grid_barrier(bar0);

    // ---- Phase B: blocks 0..383 run one (b,h) MLP each ----
    if (blk < BH) {
        const int bh = blk;
        const int b  = bh / HN;

        sidx_s[t] = gidx[b * SS + t];
        v[t] = 0.f; v[t + SS] = 0.f;
        __syncthreads();

        // scatter (per-batch permutation -> collision-free)
        {
            int sidx = sidx_s[t];
            v[sidx]      = mxr[bh * N1 + t];
            v[sidx + SS] = mxt[bh * N1 + t];
        }
        __syncthreads();

        // LayerNorm over 512
        {
            float x0 = v[t], x1 = v[t + SS];
            float s  = x0 + x1;
            float sq = x0 * x0 + x1 * x1;
#pragma unroll
            for (int off = 32; off; off >>= 1) {
                s  += __shfl_xor(s, off);
                sq += __shfl_xor(sq, off);
            }
            if (lane == 0) { red[w] = s; red[4 + w] = sq; }
            __syncthreads();
            s  = red[0] + red[1] + red[2] + red[3];
            sq = red[4] + red[5] + red[6] + red[7];
            const float mu   = s * (1.f / 512.f);
            const float var  = sq * (1.f / 512.f) - mu * mu;
            const float rstd = rsqrtf(var + 1e-5f);
            v[t]      = (x0 - mu) * rstd * ln_g[t]      + ln_b[t];
            v[t + SS] = (x1 - mu) * rstd * ln_g[t + SS] + ln_b[t + SS];
        }
        __syncthreads();

        // GEMM1: hs[t] = relu(sum_e v[e]*W1[e*256+t] + b1[t])
        {
            float a0 = b1[t], a1 = 0.f;
#pragma unroll 8
            for (int e = 0; e < SS; ++e)       a0 = fmaf(v[e], W1[e * SS + t], a0);
#pragma unroll 8
            for (int e = SS; e < 2 * SS; ++e)  a1 = fmaf(v[e], W1[e * SS + t], a1);
            hs[t] = fmaxf(a0 + a1, 0.f);
        }
        __syncthreads();

        // GEMM2: gs[.] = sigmoid(sum_f hs[f]*W2[f*512+.] + b2)
        {
            float lo0 = b2[t], lo1 = 0.f, hi0 = b2[t + SS], hi1 = 0.f;
#pragma unroll 8
            for (int f = 0; f < 128; ++f) {
                float hv = hs[f];
                lo0 = fmaf(hv, W2[f * 2 * SS + t],      lo0);
                hi0 = fmaf(hv, W2[f * 2 * SS + t + SS], hi0);
            }
#pragma unroll 8
            for (int f = 128; f < SS; ++f) {
                float hv = hs[f];
                lo1 = fmaf(hv, W2[f * 2 * SS + t],      lo1);
                hi1 = fmaf(hv, W2[f * 2 * SS + t + SS], hi1);
            }
            gs[t]      = 1.f / (1.f + expf(-(lo0 + lo1)));
            gs[t + SS] = 1.f / (1.f + expf(-(hi0 + hi1)));
        }
        __syncthreads();

        // gather per-row gates to (b,h,n1) order
        growR[bh * N1 + t] = gs[sidx_s[t]];
        growT[bh * N1 + t] = gs[sidx_s[t] + SS];
    }
    grid_barrier(bar1);

    // ---- Phase C: modulate; blocks [0,256) tir, [256,512) rgb; NT stores ---
    // Re-read should hit the Infinity Cache (read set 250MB < 256MB, NT
    // stores don't allocate -- R6 counter evidence: FETCH was exactly 250MB).
    {
        const int isRgb = blk >= C_HALF;
        const v4f*   src  = (const v4f*)(isRgb ? rgb : tir);
        const float* grow = isRgb ? growR : growT;
        v4f*         dst  = isRgb ? outRgb : outTir;

        const unsigned B0 = (unsigned)(isRgb ? blk - C_HALF : blk) * C_F4_BLK
                          + (unsigned)t;
        for (int k = 0; k < C_ITERS; k += 8) {
            v4f a[8]; float g[8];
#pragma unroll
            for (int q = 0; q < 8; ++q) a[q] = src[B0 + (unsigned)(k + q) * 256u];
#pragma unroll
            for (int q = 0; q < 8; ++q) g[q] = grow[(B0 + (unsigned)(k + q) * 256u) / 80u];
#pragma unroll
            for (int q = 0; q < 8; ++q)
                __builtin_nontemporal_store(a[q] * g[q],
                                            &dst[B0 + (unsigned)(k + q) * 256u]);
        }
    }
}

extern "C" void kernel_launch(void* const* d_in, const int* in_sizes, int n_in,
                              void* d_out, int out_size, void* d_ws, size_t ws_size,
                              hipStream_t stream)
{
    const float* attn_rgb = (const float*)d_in[0];
    const float* attn_tir = (const float*)d_in[1];
    const int*   gidx     = (const int*)  d_in[2];
    const float* ln_g     = (const float*)d_in[3];
    const float* ln_b     = (const float*)d_in[4];
    const float* W1       = (const float*)d_in[5];
    const float* b1       = (const float*)d_in[6];
    const float* W2       = (const float*)d_in[7];
    const float* b2       = (const float*)d_in[8];

    // Workspace layout: [0,256B) barrier counters; floats from 1KB on.
    unsigned* bar0 = (unsigned*)d_ws;
    unsigned* bar1 = bar0 + 64;            // separate cache line
    float* fws   = (float*)((char*)d_ws + 1024);
    float* mxr   = fws;                    // [ROWS]
    float* mxt   = mxr + ROWS;             // [ROWS]
    float* growR = mxt + ROWS;             // [ROWS]
    float* growT = growR + ROWS;           // [ROWS]

    v4f* outTir = (v4f*)d_out;             // tir_col first per reference
    v4f* outRgb = outTir + N4PT;

    // Zero the barrier counters (graph-capture-safe async memset node).
    hipMemsetAsync(d_ws, 0, 512, stream);

    k_all<<<GRID, 256, 0, stream>>>(attn_rgb, attn_tir, gidx, ln_g, ln_b,
                                    W1, b1, W2, b2, bar0, bar1,
                                    mxr, mxt, growR, growT, outTir, outRgb);
}

// Round 10
// 134.304 us; speedup vs baseline: 2.5120x; 2.5120x over previous
//
#include <hip/hip_runtime.h>
#include <hip/hip_bf16.h>
#include <math.h>

// Problem constants
#define BB   32
#define HN   12
#define N1   256
#define N2   320
#define SS   256
#define BH   (BB*HN)                 // 384
#define R4   (N2/4)                  // 80 float4 per row
#define SLICE4 ((size_t)N1*R4)       // f4 per (b,h) per tensor = 20480

typedef float v4f __attribute__((ext_vector_type(4)));

// One block of 512 threads (8 waves) per (b,h). No global workspace, no
// barriers. launch_bounds(512,4): 4 waves/SIMD -> 2 blocks/CU, VGPR cap 128.
__global__ __launch_bounds__(512, 4) void k_fused(
    const float* __restrict__ rgb, const float* __restrict__ tir,
    const int*   __restrict__ gidx,
    const float* __restrict__ ln_g, const float* __restrict__ ln_b,
    const float* __restrict__ W1,  const float* __restrict__ b1,
    const float* __restrict__ W2,  const float* __restrict__ b2,
    v4f* __restrict__ outTir, v4f* __restrict__ outRgb)
{
    __shared__ float mxs[2 * SS];    // row maxes: rgb [0,256), tir [256,512)
    __shared__ float v[2 * SS];      // scattered -> normalized vector
    __shared__ float h2[2][SS];      // GEMM1 segment partials
    __shared__ float hs[SS];         // hidden relu
    __shared__ float gs[2 * SS];     // sigmoid gates
    __shared__ float growR[SS];      // per-row gate, rgb
    __shared__ float growT[SS];      // per-row gate, tir
    __shared__ int   sidx_s[SS];
    __shared__ float red[16];

    const int bh   = (int)blockIdx.x;    // 0..383
    const int b    = bh / HN;
    const int t    = (int)threadIdx.x;   // 0..511
    const int w    = t >> 6;             // wave 0..7
    const int lane = t & 63;

    if (t < SS) sidx_s[t] = gidx[b * SS + t];
    v[t] = 0.f;

    const float* sliceR = rgb + (size_t)bh * SLICE4 * 4;
    const float* sliceT = tir + (size_t)bh * SLICE4 * 4;

    // ---- Phase A: row maxes. 512 row-units (tensor,row); 64 per wave,
    // 8-unit load batches (16 loads in flight). Tail f4s [64,80) via
    // lane-duplicated loads (no effect on max, addresses coalesce).
    for (int uu = 0; uu < 64; uu += 8) {
        const int u0 = w * 64 + uu;
        v4f a[8], b8[8];
#pragma unroll
        for (int q = 0; q < 8; ++q) {
            int u   = u0 + q;
            int row = u & 255;
            const v4f* p = (const v4f*)((u >= SS ? sliceT : sliceR)
                                        + (size_t)row * N2);
            a[q]  = p[lane];
            b8[q] = p[64 + (lane & 15)];
        }
#pragma unroll
        for (int q = 0; q < 8; ++q) {
            float m = fmaxf(fmaxf(fmaxf(a[q].x, a[q].y), fmaxf(a[q].z, a[q].w)),
                            fmaxf(fmaxf(b8[q].x, b8[q].y), fmaxf(b8[q].z, b8[q].w)));
#pragma unroll
            for (int off = 32; off; off >>= 1) m = fmaxf(m, __shfl_xor(m, off));
            if (lane == 0) mxs[u0 + q] = m;
        }
    }
    __syncthreads();

    // ---- Phase B1: scatter (per-batch permutation -> collision-free) ----
    if (t < SS) {
        int sidx = sidx_s[t];
        v[sidx]      = mxs[t];
        v[sidx + SS] = mxs[t + SS];
    }
    __syncthreads();

    // ---- Phase B2: LayerNorm over 512 (one element per thread) ----
    {
        float x  = v[t];
        float s  = x;
        float sq = x * x;
#pragma unroll
        for (int off = 32; off; off >>= 1) {
            s  += __shfl_xor(s, off);
            sq += __shfl_xor(sq, off);
        }
        if (lane == 0) { red[w] = s; red[8 + w] = sq; }
        __syncthreads();
        s  = red[0] + red[1] + red[2] + red[3] + red[4] + red[5] + red[6] + red[7];
        sq = red[8] + red[9] + red[10] + red[11] + red[12] + red[13] + red[14] + red[15];
        const float mu   = s * (1.f / 512.f);
        const float var  = sq * (1.f / 512.f) - mu * mu;
        const float rstd = rsqrtf(var + 1e-5f);
        v[t] = (x - mu) * rstd * ln_g[t] + ln_b[t];
    }
    __syncthreads();

    // ---- Phase B3: GEMM1 partials. out = t&255, seg = t>>8 (256 e each) ---
    {
        const int out = t & 255, seg = t >> 8;
        const int e0  = seg * SS;
        float a0 = (seg == 0) ? b1[out] : 0.f, a1 = 0.f;
#pragma unroll 8
        for (int e = 0; e < 128; ++e)
            a0 = fmaf(v[e0 + e],       W1[(e0 + e) * SS + out],       a0);
#pragma unroll 8
        for (int e = 128; e < 256; ++e)
            a1 = fmaf(v[e0 + e],       W1[(e0 + e) * SS + out],       a1);
        h2[seg][out] = a0 + a1;
    }
    __syncthreads();
    if (t < SS) hs[t] = fmaxf(h2[0][t] + h2[1][t], 0.f);
    __syncthreads();

    // ---- Phase B4: GEMM2, one output per thread (512 outputs) ----
    {
        float a0 = b2[t], a1 = 0.f;
#pragma unroll 8
        for (int f = 0; f < 128; ++f)      a0 = fmaf(hs[f], W2[f * 2 * SS + t], a0);
#pragma unroll 8
        for (int f = 128; f < 256; ++f)    a1 = fmaf(hs[f], W2[f * 2 * SS + t], a1);
        gs[t] = 1.f / (1.f + expf(-(a0 + a1)));
    }
    __syncthreads();

    // ---- Phase B5: gather per-row gates ----
    if (t < SS) {
        growR[t] = gs[sidx_s[t]];
        growT[t] = gs[sidx_s[t] + SS];
    }
    __syncthreads();

    // ---- Phase C: hot re-read own slice, scale, NT-store ----
    // 40960 f4 (both tensors), flat: i = k*512 + t; tir first half.
    {
        const v4f* srcR4 = (const v4f*)sliceR;
        const v4f* srcT4 = (const v4f*)sliceT;
        v4f* dstR = outRgb + (size_t)bh * SLICE4;
        v4f* dstT = outTir + (size_t)bh * SLICE4;
        for (int k = 0; k < 80; k += 8) {
            v4f a[8]; float g[8];
#pragma unroll
            for (int q = 0; q < 8; ++q) {
                unsigned i = (unsigned)(k + q) * 512u + (unsigned)t;  // < 40960
                int isRgb  = i >= 20480u;
                unsigned j = isRgb ? i - 20480u : i;
                a[q] = isRgb ? srcR4[j] : srcT4[j];
                g[q] = (isRgb ? growR : growT)[j / 80u];
            }
#pragma unroll
            for (int q = 0; q < 8; ++q) {
                unsigned i = (unsigned)(k + q) * 512u + (unsigned)t;
                int isRgb  = i >= 20480u;
                unsigned j = isRgb ? i - 20480u : i;
                __builtin_nontemporal_store(a[q] * g[q],
                                            (isRgb ? dstR : dstT) + j);
            }
        }
    }
}

extern "C" void kernel_launch(void* const* d_in, const int* in_sizes, int n_in,
                              void* d_out, int out_size, void* d_ws, size_t ws_size,
                              hipStream_t stream)
{
    const float* attn_rgb = (const float*)d_in[0];
    const float* attn_tir = (const float*)d_in[1];
    const int*   gidx     = (const int*)  d_in[2];
    const float* ln_g     = (const float*)d_in[3];
    const float* ln_b     = (const float*)d_in[4];
    const float* W1       = (const float*)d_in[5];
    const float* b1       = (const float*)d_in[6];
    const float* W2       = (const float*)d_in[7];
    const float* b2       = (const float*)d_in[8];

    v4f* outTir = (v4f*)d_out;               // tir_col first per reference
    v4f* outRgb = outTir + (size_t)BH * SLICE4;

    k_fused<<<BH, 512, 0, stream>>>(attn_rgb, attn_tir, gidx, ln_g, ln_b,
                                    W1, b1, W2, b2, outTir, outRgb);
}